// Round 3
// baseline (385.056 us; speedup 1.0000x reference)
//
#include <hip/hip_runtime.h>

// MultiHeadedAttention: B=2, S=2048, D=1024, H=16, DH=64.
// Inputs/outputs are FLOAT32 (per reference); internal pipeline bf16 MFMA.
// Pipeline: QKV proj GEMMs -> flash attention (causal) -> output proj GEMM.

typedef __bf16 bf16x8 __attribute__((ext_vector_type(8)));
typedef float  f32x4  __attribute__((ext_vector_type(4)));

#define B_  2
#define S_  2048
#define D_  1024
#define H_  16
#define DH_ 64

#define NEG_ 1.0e30f  // finite "-inf" sentinel: exp(-1e30 - m) == 0, no inf-inf NaN

// ---- async 16B global -> LDS copy (lane l writes lds_base + l*16B) ---------
__device__ __forceinline__ void load_lds16(const __bf16* g, __bf16* lds_base) {
    __builtin_amdgcn_global_load_lds(
        (const __attribute__((address_space(1))) void*)g,
        (__attribute__((address_space(3))) void*)lds_base,
        16, 0, 0);
}

// ---- load 8 consecutive fp32, convert to packed bf16x8 ---------------------
__device__ __forceinline__ bf16x8 cvt8(const float* __restrict__ p) {
    const float4 a = *(const float4*)p;
    const float4 b = *(const float4*)(p + 4);
    bf16x8 r;
    r[0] = (__bf16)a.x; r[1] = (__bf16)a.y; r[2] = (__bf16)a.z; r[3] = (__bf16)a.w;
    r[4] = (__bf16)b.x; r[5] = (__bf16)b.y; r[6] = (__bf16)b.z; r[7] = (__bf16)b.w;
    return r;
}

// ---- 128x128 GEMM core: Y[m,n] = sum_k X[m,k] * W[n,k]  (fp32 in, bf16 MFMA)
// 256 threads = 4 waves in 2x2; each wave computes 4x4 grid of 16x16 tiles.
__device__ __forceinline__ void gemm128_f32(const float* __restrict__ X,
                                            const float* __restrict__ W,
                                            int m0, int n0, int K,
                                            __bf16* As, __bf16* Bs,
                                            f32x4 acc[4][4]) {
    const int tid  = threadIdx.x;
    const int wave = tid >> 6, lane = tid & 63;
    const int row  = lane & 15, quad = lane >> 4;
    const int wm   = wave >> 1, wn = wave & 1;
    const int arow = lane >> 2;        // 0..15 row within 16-row chunk
    const int acol = (lane & 3) * 8;   // element offset within 32-elem row

    const f32x4 fzero = {0.f, 0.f, 0.f, 0.f};
#pragma unroll
    for (int mt = 0; mt < 4; ++mt)
#pragma unroll
        for (int nt = 0; nt < 4; ++nt) acc[mt][nt] = fzero;

    for (int k0 = 0; k0 < K; k0 += 32) {
#pragma unroll
        for (int c = 0; c < 2; ++c) {
            const int j = wave * 2 + c;  // chunk 0..7, 16 rows each
            *(bf16x8*)(As + j * 512 + arow * 32 + acol) =
                cvt8(X + (size_t)(m0 + j * 16 + arow) * K + k0 + acol);
            *(bf16x8*)(Bs + j * 512 + arow * 32 + acol) =
                cvt8(W + (size_t)(n0 + j * 16 + arow) * K + k0 + acol);
        }
        __syncthreads();
        bf16x8 af[4], bfv[4];
#pragma unroll
        for (int t = 0; t < 4; ++t) {
            af[t]  = *(const bf16x8*)(As + (wm * 64 + t * 16 + row) * 32 + quad * 8);
            bfv[t] = *(const bf16x8*)(Bs + (wn * 64 + t * 16 + row) * 32 + quad * 8);
        }
#pragma unroll
        for (int mt = 0; mt < 4; ++mt)
#pragma unroll
            for (int nt = 0; nt < 4; ++nt)
                acc[mt][nt] = __builtin_amdgcn_mfma_f32_16x16x32_bf16(
                    af[mt], bfv[nt], acc[mt][nt], 0, 0, 0);
        __syncthreads();
    }
}

// ---- QKV projection: z selects Q/K/V. Writes bf16 head-split layouts. ------
__global__ void qkv_kernel(const float* __restrict__ q_in, const float* __restrict__ k_in,
                           const float* __restrict__ v_in,
                           const float* __restrict__ wq, const float* __restrict__ wk,
                           const float* __restrict__ wv,
                           const float* __restrict__ bq, const float* __restrict__ bk,
                           const float* __restrict__ bv,
                           __bf16* __restrict__ q_ws, __bf16* __restrict__ k_ws,
                           __bf16* __restrict__ v_ws) {
    __shared__ __align__(16) __bf16 As[128 * 32];
    __shared__ __align__(16) __bf16 Bs[128 * 32];
    const int mode = blockIdx.z;
    const float* X    = mode == 0 ? q_in : mode == 1 ? k_in : v_in;
    const float* W    = mode == 0 ? wq : mode == 1 ? wk : wv;
    const float* bias = mode == 0 ? bq : mode == 1 ? bk : bv;
    const int m0 = blockIdx.y * 128, n0 = blockIdx.x * 128;

    f32x4 acc[4][4];
    gemm128_f32(X, W, m0, n0, D_, As, Bs, acc);

    const int tid = threadIdx.x;
    const int wave = tid >> 6, lane = tid & 63;
    const int row = lane & 15, quad = lane >> 4;
    const int wm = wave >> 1, wn = wave & 1;

#pragma unroll
    for (int nt = 0; nt < 4; ++nt) {
        const int n  = n0 + wn * 64 + nt * 16 + row;
        const float bf = bias[n];
        const int h = n >> 6, dh = n & 63;
#pragma unroll
        for (int mt = 0; mt < 4; ++mt) {
#pragma unroll
            for (int r = 0; r < 4; ++r) {
                const int m = m0 + wm * 64 + mt * 16 + quad * 4 + r;
                const int bb = m >> 11, s = m & (S_ - 1);
                const float val = acc[mt][nt][r] + bf;
                if (mode == 0)       // Q: (B,H,S,DH), pre-scaled by 1/sqrt(DH)
                    q_ws[(((size_t)bb * H_ + h) * S_ + s) * DH_ + dh] = (__bf16)(val * 0.125f);
                else if (mode == 1)  // K: (B,H,S,DH)
                    k_ws[(((size_t)bb * H_ + h) * S_ + s) * DH_ + dh] = (__bf16)val;
                else                 // V: transposed (B,H,DH,S)
                    v_ws[(((size_t)bb * H_ + h) * DH_ + dh) * S_ + s] = (__bf16)val;
            }
        }
    }
}

// ---- Flash attention (causal): 1 WG per (bh, 128-row Q tile). fp32 out. ----
__global__ void attn_kernel(const __bf16* __restrict__ q_ws, const __bf16* __restrict__ k_ws,
                            const __bf16* __restrict__ v_ws, float* __restrict__ att) {
    __shared__ __align__(16) __bf16 Ks[128 * 64];    // [key][dh]
    __shared__ __align__(16) __bf16 Vs[64 * 128];    // [dh][key]  (transposed V)
    __shared__ __align__(16) __bf16 Ps[4 * 32 * 128];// per-wave P block [32][128]

    const int bh = blockIdx.x;   // b*H + h
    const int qt = blockIdx.y;   // Q tile (128 rows)
    const int tid = threadIdx.x, wave = tid >> 6, lane = tid & 63;
    const int row = lane & 15, quad = lane >> 4;

    const __bf16* Qg = q_ws + ((size_t)bh * S_ + qt * 128 + wave * 32) * DH_;
    const __bf16* Kg = k_ws + (size_t)bh * S_ * DH_;
    const __bf16* Vg = v_ws + (size_t)bh * DH_ * S_;

    // Q fragments: A layout, rows wave*32 + mt*16 + (lane&15), k = ks*32+quad*8..+7
    bf16x8 qf[2][2];
#pragma unroll
    for (int mt = 0; mt < 2; ++mt)
#pragma unroll
        for (int ks = 0; ks < 2; ++ks)
            qf[mt][ks] = *(const bf16x8*)(Qg + (mt * 16 + row) * DH_ + ks * 32 + quad * 8);

    const f32x4 fzero = {0.f, 0.f, 0.f, 0.f};
    f32x4 oacc[2][4];
    float m_st[2][4], l_st[2][4];
#pragma unroll
    for (int mt = 0; mt < 2; ++mt) {
#pragma unroll
        for (int dt = 0; dt < 4; ++dt) oacc[mt][dt] = fzero;
#pragma unroll
        for (int r = 0; r < 4; ++r) { m_st[mt][r] = -NEG_; l_st[mt][r] = 0.f; }
    }

    for (int kv = 0; kv <= qt; ++kv) {
        // stage K tile (contiguous 16KB) and Vt tile (64 rows x 256B)
#pragma unroll
        for (int c = 0; c < 4; ++c) {
            const int ck = wave * 4 + c;  // chunk 0..15, 1KB each
            load_lds16(Kg + (size_t)kv * 128 * DH_ + ck * 512 + lane * 8, Ks + ck * 512);
            load_lds16(Vg + (size_t)(ck * 4 + (lane >> 4)) * S_ + kv * 128 + (lane & 15) * 8,
                       Vs + ck * 512);
        }
        __syncthreads();

        // S = Q K^T (Q pre-scaled); 2 m-tiles x 8 n-tiles per wave
        f32x4 sacc[2][8];
#pragma unroll
        for (int mt = 0; mt < 2; ++mt)
#pragma unroll
            for (int nt = 0; nt < 8; ++nt) sacc[mt][nt] = fzero;
#pragma unroll
        for (int nt = 0; nt < 8; ++nt) {
            bf16x8 kf0 = *(const bf16x8*)(Ks + (nt * 16 + row) * DH_ + quad * 8);
            bf16x8 kf1 = *(const bf16x8*)(Ks + (nt * 16 + row) * DH_ + 32 + quad * 8);
#pragma unroll
            for (int mt = 0; mt < 2; ++mt) {
                sacc[mt][nt] = __builtin_amdgcn_mfma_f32_16x16x32_bf16(qf[mt][0], kf0, sacc[mt][nt], 0, 0, 0);
                sacc[mt][nt] = __builtin_amdgcn_mfma_f32_16x16x32_bf16(qf[mt][1], kf1, sacc[mt][nt], 0, 0, 0);
            }
        }

        if (kv == qt) {  // causal mask on diagonal tile: col > row -> masked
#pragma unroll
            for (int mt = 0; mt < 2; ++mt)
#pragma unroll
                for (int nt = 0; nt < 8; ++nt) {
                    const int cloc = nt * 16 + row;
#pragma unroll
                    for (int r = 0; r < 4; ++r) {
                        const int rloc = wave * 32 + mt * 16 + quad * 4 + r;
                        if (cloc > rloc) sacc[mt][nt][r] = -NEG_;
                    }
                }
        }

        // online softmax per row (each row lives in one 16-lane group = same quad)
        float alpha_a[2][4];
#pragma unroll
        for (int mt = 0; mt < 2; ++mt) {
#pragma unroll
            for (int r = 0; r < 4; ++r) {
                float mx = -NEG_;
#pragma unroll
                for (int nt = 0; nt < 8; ++nt) mx = fmaxf(mx, sacc[mt][nt][r]);
                mx = fmaxf(mx, __shfl_xor(mx, 1));
                mx = fmaxf(mx, __shfl_xor(mx, 2));
                mx = fmaxf(mx, __shfl_xor(mx, 4));
                mx = fmaxf(mx, __shfl_xor(mx, 8));
                const float mnew = fmaxf(m_st[mt][r], mx);
                float sum = 0.f;
#pragma unroll
                for (int nt = 0; nt < 8; ++nt) {
                    const float p = __expf(sacc[mt][nt][r] - mnew);
                    sum += p;
                    Ps[wave * 4096 + (mt * 16 + quad * 4 + r) * 128 + nt * 16 + row] = (__bf16)p;
                }
                sum += __shfl_xor(sum, 1);
                sum += __shfl_xor(sum, 2);
                sum += __shfl_xor(sum, 4);
                sum += __shfl_xor(sum, 8);
                const float alpha = __expf(m_st[mt][r] - mnew);
                l_st[mt][r] = l_st[mt][r] * alpha + sum;
                m_st[mt][r] = mnew;
                alpha_a[mt][r] = alpha;
            }
        }
#pragma unroll
        for (int mt = 0; mt < 2; ++mt)
#pragma unroll
            for (int dt = 0; dt < 4; ++dt)
#pragma unroll
                for (int r = 0; r < 4; ++r) oacc[mt][dt][r] *= alpha_a[mt][r];

        // make P visible (full barrier: conservative but airtight)
        __syncthreads();

        // O += P V : A = P (32x128), B = Vt (k=key, n=dh)
#pragma unroll
        for (int kc = 0; kc < 4; ++kc) {
            bf16x8 pf0 = *(const bf16x8*)(Ps + wave * 4096 + (row) * 128 + kc * 32 + quad * 8);
            bf16x8 pf1 = *(const bf16x8*)(Ps + wave * 4096 + (16 + row) * 128 + kc * 32 + quad * 8);
#pragma unroll
            for (int dt = 0; dt < 4; ++dt) {
                bf16x8 vf = *(const bf16x8*)(Vs + (dt * 16 + row) * 128 + kc * 32 + quad * 8);
                oacc[0][dt] = __builtin_amdgcn_mfma_f32_16x16x32_bf16(pf0, vf, oacc[0][dt], 0, 0, 0);
                oacc[1][dt] = __builtin_amdgcn_mfma_f32_16x16x32_bf16(pf1, vf, oacc[1][dt], 0, 0, 0);
            }
        }
        __syncthreads();  // all waves done with Ks/Vs before next staging
    }

    // epilogue: O / l, write merged layout (B, S, H*DH) in fp32
    const int b = bh >> 4, h = bh & 15;
#pragma unroll
    for (int mt = 0; mt < 2; ++mt) {
#pragma unroll
        for (int r = 0; r < 4; ++r) {
            const float inv = 1.f / l_st[mt][r];
            const int s = qt * 128 + wave * 32 + mt * 16 + quad * 4 + r;
#pragma unroll
            for (int dt = 0; dt < 4; ++dt) {
                att[((size_t)b * S_ + s) * D_ + h * DH_ + dt * 16 + row] =
                    oacc[mt][dt][r] * inv;
            }
        }
    }
}

// ---- Output projection: out = att @ W_O^T + b_O (fp32 in/out) -------------
__global__ void oproj_kernel(const float* __restrict__ attn, const float* __restrict__ wo,
                             const float* __restrict__ bo, float* __restrict__ out) {
    __shared__ __align__(16) __bf16 As[128 * 32];
    __shared__ __align__(16) __bf16 Bs[128 * 32];
    const int m0 = blockIdx.y * 128, n0 = blockIdx.x * 128;

    f32x4 acc[4][4];
    gemm128_f32(attn, wo, m0, n0, D_, As, Bs, acc);

    const int tid = threadIdx.x;
    const int wave = tid >> 6, lane = tid & 63;
    const int row = lane & 15, quad = lane >> 4;
    const int wm = wave >> 1, wn = wave & 1;

#pragma unroll
    for (int nt = 0; nt < 4; ++nt) {
        const int n = n0 + wn * 64 + nt * 16 + row;
        const float bf = bo[n];
#pragma unroll
        for (int mt = 0; mt < 4; ++mt) {
#pragma unroll
            for (int r = 0; r < 4; ++r) {
                const int m = m0 + wm * 64 + mt * 16 + quad * 4 + r;
                out[(size_t)m * D_ + n] = acc[mt][nt][r] + bf;
            }
        }
    }
}

extern "C" void kernel_launch(void* const* d_in, const int* in_sizes, int n_in,
                              void* d_out, int out_size, void* d_ws, size_t ws_size,
                              hipStream_t stream) {
    const float* q_in = (const float*)d_in[0];
    const float* k_in = (const float*)d_in[1];
    const float* v_in = (const float*)d_in[2];
    const float* wq   = (const float*)d_in[3];
    const float* bq   = (const float*)d_in[4];
    const float* wk   = (const float*)d_in[5];
    const float* bk   = (const float*)d_in[6];
    const float* wv   = (const float*)d_in[7];
    const float* bv   = (const float*)d_in[8];
    const float* wo   = (const float*)d_in[9];
    const float* bo   = (const float*)d_in[10];

    char* ws = (char*)d_ws;
    const size_t TENS = (size_t)B_ * S_ * D_;  // 4,194,304 elems
    __bf16* q_ws = (__bf16*)ws;                          // 8 MB
    __bf16* k_ws = (__bf16*)(ws + 2 * TENS);             // 8 MB
    __bf16* v_ws = (__bf16*)(ws + 4 * TENS);             // 8 MB
    float*  att  = (float*)(ws + 6 * TENS);              // 16 MB
    float*  out  = (float*)d_out;

    qkv_kernel<<<dim3(D_ / 128, (B_ * S_) / 128, 3), 256, 0, stream>>>(
        q_in, k_in, v_in, wq, wk, wv, bq, bk, bv, q_ws, k_ws, v_ws);
    attn_kernel<<<dim3(B_ * H_, S_ / 128), 256, 0, stream>>>(q_ws, k_ws, v_ws, att);
    oproj_kernel<<<dim3(D_ / 128, (B_ * S_) / 128), 256, 0, stream>>>(att, wo, bo, out);
}

// Round 4
// 281.415 us; speedup vs baseline: 1.3683x; 1.3683x over previous
//
#include <hip/hip_runtime.h>

// MultiHeadedAttention: B=2, S=2048, D=1024, H=16, DH=64.
// fp32 in/out; internal bf16 MFMA pipeline.
// cvt (fp32->bf16) -> QKV bf16 GEMMs -> flash attention (static-max) -> oproj.

typedef __bf16 bf16x8 __attribute__((ext_vector_type(8)));
typedef float  f32x4  __attribute__((ext_vector_type(4)));

#define B_  2
#define S_  2048
#define D_  1024
#define H_  16
#define DH_ 64

#define NEG_ 1.0e30f              // finite "-inf": exp2 -> 0, no inf-inf NaN
#define M2_  5.77078016f          // static softmax max: 4.0 * log2(e)
#define QSCALE_ 0.18033688f       // 1/sqrt(64) * log2(e): scores in log2 domain

#if __has_builtin(__builtin_amdgcn_exp2f)
#define EXP2(x) __builtin_amdgcn_exp2f(x)
#else
#define EXP2(x) __builtin_exp2f(x)
#endif

// ---- async 16B global -> LDS copy (lane l writes lds_base + l*16B) ---------
__device__ __forceinline__ void load_lds16(const __bf16* g, __bf16* lds_base) {
    __builtin_amdgcn_global_load_lds(
        (const __attribute__((address_space(1))) void*)g,
        (__attribute__((address_space(3))) void*)lds_base,
        16, 0, 0);
}

// ---- load 8 consecutive fp32, convert to packed bf16x8 ---------------------
__device__ __forceinline__ bf16x8 cvt8(const float* __restrict__ p) {
    const float4 a = *(const float4*)p;
    const float4 b = *(const float4*)(p + 4);
    bf16x8 r;
    r[0] = (__bf16)a.x; r[1] = (__bf16)a.y; r[2] = (__bf16)a.z; r[3] = (__bf16)a.w;
    r[4] = (__bf16)b.x; r[5] = (__bf16)b.y; r[6] = (__bf16)b.z; r[7] = (__bf16)b.w;
    return r;
}

// ---- fp32 -> bf16 conversion pass: z picks tensor --------------------------
__global__ void cvt_kernel(const float* __restrict__ q, const float* __restrict__ k,
                           const float* __restrict__ v,
                           const float* __restrict__ wq, const float* __restrict__ wk,
                           const float* __restrict__ wv, const float* __restrict__ wo,
                           __bf16* __restrict__ qb, __bf16* __restrict__ kb,
                           __bf16* __restrict__ vb,
                           __bf16* __restrict__ wqb, __bf16* __restrict__ wkb,
                           __bf16* __restrict__ wvb, __bf16* __restrict__ wob) {
    const int z = blockIdx.z;
    const float* src; __bf16* dst; size_t n;
    switch (z) {
        case 0: src = q;  dst = qb;  n = (size_t)B_ * S_ * D_; break;
        case 1: src = k;  dst = kb;  n = (size_t)B_ * S_ * D_; break;
        case 2: src = v;  dst = vb;  n = (size_t)B_ * S_ * D_; break;
        case 3: src = wq; dst = wqb; n = (size_t)D_ * D_; break;
        case 4: src = wk; dst = wkb; n = (size_t)D_ * D_; break;
        case 5: src = wv; dst = wvb; n = (size_t)D_ * D_; break;
        default: src = wo; dst = wob; n = (size_t)D_ * D_; break;
    }
    const size_t i = ((size_t)blockIdx.x * 256 + threadIdx.x) * 8;
    if (i >= n) return;
    *(bf16x8*)(dst + i) = cvt8(src + i);
}

// ---- 128x128 bf16 GEMM core: Y[m,n] = sum_k X[m,k]*W[n,k], global_load_lds -
__device__ __forceinline__ void gemm128_bf(const __bf16* __restrict__ X,
                                           const __bf16* __restrict__ W,
                                           int m0, int n0, int K,
                                           __bf16* As, __bf16* Bs,
                                           f32x4 acc[4][4]) {
    const int tid  = threadIdx.x;
    const int wave = tid >> 6, lane = tid & 63;
    const int row  = lane & 15, quad = lane >> 4;
    const int wm   = wave >> 1, wn = wave & 1;
    const int arow = lane >> 2;        // 0..15 row within 16-row chunk
    const int acol = (lane & 3) * 8;   // elem offset within 32-elem row

    const f32x4 fzero = {0.f, 0.f, 0.f, 0.f};
#pragma unroll
    for (int mt = 0; mt < 4; ++mt)
#pragma unroll
        for (int nt = 0; nt < 4; ++nt) acc[mt][nt] = fzero;

    for (int k0 = 0; k0 < K; k0 += 32) {
#pragma unroll
        for (int c = 0; c < 2; ++c) {
            const int j = wave * 2 + c;  // chunk 0..7, 16 rows each
            load_lds16(X + (size_t)(m0 + j * 16 + arow) * K + k0 + acol, As + j * 512);
            load_lds16(W + (size_t)(n0 + j * 16 + arow) * K + k0 + acol, Bs + j * 512);
        }
        __syncthreads();
        bf16x8 af[4], bfv[4];
#pragma unroll
        for (int t = 0; t < 4; ++t) {
            af[t]  = *(const bf16x8*)(As + (wm * 64 + t * 16 + row) * 32 + quad * 8);
            bfv[t] = *(const bf16x8*)(Bs + (wn * 64 + t * 16 + row) * 32 + quad * 8);
        }
#pragma unroll
        for (int mt = 0; mt < 4; ++mt)
#pragma unroll
            for (int nt = 0; nt < 4; ++nt)
                acc[mt][nt] = __builtin_amdgcn_mfma_f32_16x16x32_bf16(
                    af[mt], bfv[nt], acc[mt][nt], 0, 0, 0);
        __syncthreads();
    }
}

// ---- QKV projection (bf16): z selects Q/K/V. Head-split layouts. ----------
__global__ void qkv_kernel(const __bf16* __restrict__ qb, const __bf16* __restrict__ kb,
                           const __bf16* __restrict__ vb,
                           const __bf16* __restrict__ wqb, const __bf16* __restrict__ wkb,
                           const __bf16* __restrict__ wvb,
                           const float* __restrict__ bq, const float* __restrict__ bk,
                           const float* __restrict__ bv,
                           __bf16* __restrict__ q_ws, __bf16* __restrict__ k_ws,
                           __bf16* __restrict__ v_ws) {
    __shared__ __align__(16) __bf16 As[128 * 32];
    __shared__ __align__(16) __bf16 Bs[128 * 32];
    const int mode = blockIdx.z;
    const __bf16* X    = mode == 0 ? qb : mode == 1 ? kb : vb;
    const __bf16* W    = mode == 0 ? wqb : mode == 1 ? wkb : wvb;
    const float*  bias = mode == 0 ? bq : mode == 1 ? bk : bv;
    const int m0 = blockIdx.y * 128, n0 = blockIdx.x * 128;

    f32x4 acc[4][4];
    gemm128_bf(X, W, m0, n0, D_, As, Bs, acc);

    const int tid = threadIdx.x;
    const int wave = tid >> 6, lane = tid & 63;
    const int row = lane & 15, quad = lane >> 4;
    const int wm = wave >> 1, wn = wave & 1;

#pragma unroll
    for (int nt = 0; nt < 4; ++nt) {
        const int n  = n0 + wn * 64 + nt * 16 + row;
        const float bf = bias[n];
        const int h = n >> 6, dh = n & 63;
#pragma unroll
        for (int mt = 0; mt < 4; ++mt) {
#pragma unroll
            for (int r = 0; r < 4; ++r) {
                const int m = m0 + wm * 64 + mt * 16 + quad * 4 + r;
                const int bb = m >> 11, s = m & (S_ - 1);
                const float val = acc[mt][nt][r] + bf;
                if (mode == 0)       // Q: (B,H,S,DH), scaled to log2 domain
                    q_ws[(((size_t)bb * H_ + h) * S_ + s) * DH_ + dh] = (__bf16)(val * QSCALE_);
                else if (mode == 1)  // K: (B,H,S,DH)
                    k_ws[(((size_t)bb * H_ + h) * S_ + s) * DH_ + dh] = (__bf16)val;
                else                 // V: transposed (B,H,DH,S)
                    v_ws[(((size_t)bb * H_ + h) * DH_ + dh) * S_ + s] = (__bf16)val;
            }
        }
    }
}

// ---- Flash attention, static-max softmax. bf16 att out. -------------------
__global__ void attn_kernel(const __bf16* __restrict__ q_ws, const __bf16* __restrict__ k_ws,
                            const __bf16* __restrict__ v_ws, __bf16* __restrict__ att) {
    __shared__ __align__(16) __bf16 Ks[128 * 64];    // [key][dh]
    __shared__ __align__(16) __bf16 Vs[64 * 128];    // [dh][key]  (transposed V)
    __shared__ __align__(16) __bf16 Ps[4 * 32 * 128];// per-wave P block [32][128]

    const int bh = blockIdx.x;   // b*H + h
    const int qt = blockIdx.y;   // Q tile (128 rows)
    const int tid = threadIdx.x, wave = tid >> 6, lane = tid & 63;
    const int row = lane & 15, quad = lane >> 4;

    const __bf16* Qg = q_ws + ((size_t)bh * S_ + qt * 128 + wave * 32) * DH_;
    const __bf16* Kg = k_ws + (size_t)bh * S_ * DH_;
    const __bf16* Vg = v_ws + (size_t)bh * DH_ * S_;

    // Q fragments: A layout, rows wave*32 + mt*16 + row, k = ks*32+quad*8..+7
    bf16x8 qf[2][2];
#pragma unroll
    for (int mt = 0; mt < 2; ++mt)
#pragma unroll
        for (int ks = 0; ks < 2; ++ks)
            qf[mt][ks] = *(const bf16x8*)(Qg + (mt * 16 + row) * DH_ + ks * 32 + quad * 8);

    // all-ones B fragment (register constant) for row-sum via MFMA
    bf16x8 onesf;
#pragma unroll
    for (int i = 0; i < 8; ++i) onesf[i] = (__bf16)1.0f;

    const f32x4 fzero = {0.f, 0.f, 0.f, 0.f};
    f32x4 oacc[2][4];   // O accumulator
    f32x4 lacc[2];      // row-sum accumulator (col-redundant)
#pragma unroll
    for (int mt = 0; mt < 2; ++mt) {
#pragma unroll
        for (int dt = 0; dt < 4; ++dt) oacc[mt][dt] = fzero;
        lacc[mt] = fzero;
    }

    for (int kv = 0; kv <= qt; ++kv) {
        // stage K tile (16KB) and Vt tile (64 rows x 256B)
#pragma unroll
        for (int c = 0; c < 4; ++c) {
            const int ck = wave * 4 + c;  // chunk 0..15, 1KB each
            load_lds16(Kg + (size_t)kv * 128 * DH_ + ck * 512 + lane * 8, Ks + ck * 512);
            load_lds16(Vg + (size_t)(ck * 4 + (lane >> 4)) * S_ + kv * 128 + (lane & 15) * 8,
                       Vs + ck * 512);
        }
        __syncthreads();

        // S = Q K^T (log2 domain, Q pre-scaled)
        f32x4 sacc[2][8];
#pragma unroll
        for (int mt = 0; mt < 2; ++mt)
#pragma unroll
            for (int nt = 0; nt < 8; ++nt) sacc[mt][nt] = fzero;
#pragma unroll
        for (int nt = 0; nt < 8; ++nt) {
            bf16x8 kf0 = *(const bf16x8*)(Ks + (nt * 16 + row) * DH_ + quad * 8);
            bf16x8 kf1 = *(const bf16x8*)(Ks + (nt * 16 + row) * DH_ + 32 + quad * 8);
#pragma unroll
            for (int mt = 0; mt < 2; ++mt) {
                sacc[mt][nt] = __builtin_amdgcn_mfma_f32_16x16x32_bf16(qf[mt][0], kf0, sacc[mt][nt], 0, 0, 0);
                sacc[mt][nt] = __builtin_amdgcn_mfma_f32_16x16x32_bf16(qf[mt][1], kf1, sacc[mt][nt], 0, 0, 0);
            }
        }

        if (kv == qt) {  // causal mask on diagonal tile: col > row -> masked
#pragma unroll
            for (int mt = 0; mt < 2; ++mt)
#pragma unroll
                for (int nt = 0; nt < 8; ++nt) {
                    const int cloc = nt * 16 + row;
#pragma unroll
                    for (int r = 0; r < 4; ++r) {
                        const int rloc = wave * 32 + mt * 16 + quad * 4 + r;
                        if (cloc > rloc) sacc[mt][nt][r] = -NEG_;
                    }
                }
        }

        // static-max softmax numerator: p = 2^(s - M2); masked -> 0
#pragma unroll
        for (int mt = 0; mt < 2; ++mt)
#pragma unroll
            for (int r = 0; r < 4; ++r)
#pragma unroll
                for (int nt = 0; nt < 8; ++nt) {
                    const float p = EXP2(sacc[mt][nt][r] - M2_);
                    Ps[wave * 4096 + (mt * 16 + quad * 4 + r) * 128 + nt * 16 + row] = (__bf16)p;
                }

        // O += P V ; l += P 1  (Ps wave-private: compiler lgkmcnt covers RAW)
#pragma unroll
        for (int kc = 0; kc < 4; ++kc) {
            bf16x8 pf0 = *(const bf16x8*)(Ps + wave * 4096 + (row) * 128 + kc * 32 + quad * 8);
            bf16x8 pf1 = *(const bf16x8*)(Ps + wave * 4096 + (16 + row) * 128 + kc * 32 + quad * 8);
#pragma unroll
            for (int dt = 0; dt < 4; ++dt) {
                bf16x8 vf = *(const bf16x8*)(Vs + (dt * 16 + row) * 128 + kc * 32 + quad * 8);
                oacc[0][dt] = __builtin_amdgcn_mfma_f32_16x16x32_bf16(pf0, vf, oacc[0][dt], 0, 0, 0);
                oacc[1][dt] = __builtin_amdgcn_mfma_f32_16x16x32_bf16(pf1, vf, oacc[1][dt], 0, 0, 0);
            }
            lacc[0] = __builtin_amdgcn_mfma_f32_16x16x32_bf16(pf0, onesf, lacc[0], 0, 0, 0);
            lacc[1] = __builtin_amdgcn_mfma_f32_16x16x32_bf16(pf1, onesf, lacc[1], 0, 0, 0);
        }
        __syncthreads();  // all waves done with Ks/Vs before next staging
    }

    // epilogue: O / l, write merged layout (B, S, H*DH) in bf16
    const int b = bh >> 4, h = bh & 15;
#pragma unroll
    for (int mt = 0; mt < 2; ++mt) {
#pragma unroll
        for (int r = 0; r < 4; ++r) {
            const float inv = 1.f / lacc[mt][r];
            const int s = qt * 128 + wave * 32 + mt * 16 + quad * 4 + r;
#pragma unroll
            for (int dt = 0; dt < 4; ++dt) {
                att[((size_t)b * S_ + s) * D_ + h * DH_ + dt * 16 + row] =
                    (__bf16)(oacc[mt][dt][r] * inv);
            }
        }
    }
}

// ---- Output projection: out = att @ W_O^T + b_O (bf16 in, fp32 out) -------
__global__ void oproj_kernel(const __bf16* __restrict__ attn, const __bf16* __restrict__ wob,
                             const float* __restrict__ bo, float* __restrict__ out) {
    __shared__ __align__(16) __bf16 As[128 * 32];
    __shared__ __align__(16) __bf16 Bs[128 * 32];
    const int m0 = blockIdx.y * 128, n0 = blockIdx.x * 128;

    f32x4 acc[4][4];
    gemm128_bf(attn, wob, m0, n0, D_, As, Bs, acc);

    const int tid = threadIdx.x;
    const int wave = tid >> 6, lane = tid & 63;
    const int row = lane & 15, quad = lane >> 4;
    const int wm = wave >> 1, wn = wave & 1;

#pragma unroll
    for (int nt = 0; nt < 4; ++nt) {
        const int n = n0 + wn * 64 + nt * 16 + row;
        const float bf = bo[n];
#pragma unroll
        for (int mt = 0; mt < 4; ++mt) {
#pragma unroll
            for (int r = 0; r < 4; ++r) {
                const int m = m0 + wm * 64 + mt * 16 + quad * 4 + r;
                out[(size_t)m * D_ + n] = acc[mt][nt][r] + bf;
            }
        }
    }
}

extern "C" void kernel_launch(void* const* d_in, const int* in_sizes, int n_in,
                              void* d_out, int out_size, void* d_ws, size_t ws_size,
                              hipStream_t stream) {
    const float* q_in = (const float*)d_in[0];
    const float* k_in = (const float*)d_in[1];
    const float* v_in = (const float*)d_in[2];
    const float* wq   = (const float*)d_in[3];
    const float* bq   = (const float*)d_in[4];
    const float* wk   = (const float*)d_in[5];
    const float* bk   = (const float*)d_in[6];
    const float* wv   = (const float*)d_in[7];
    const float* bv   = (const float*)d_in[8];
    const float* wo   = (const float*)d_in[9];
    const float* bo   = (const float*)d_in[10];

    char* ws = (char*)d_ws;
    const size_t MB = 1024 * 1024;
    __bf16* qb   = (__bf16*)(ws);            // 8 MB
    __bf16* kb   = (__bf16*)(ws + 8 * MB);   // 8 MB
    __bf16* vb   = (__bf16*)(ws + 16 * MB);  // 8 MB
    __bf16* wqb  = (__bf16*)(ws + 24 * MB);  // 2 MB
    __bf16* wkb  = (__bf16*)(ws + 26 * MB);  // 2 MB
    __bf16* wvb  = (__bf16*)(ws + 28 * MB);  // 2 MB
    __bf16* wob  = (__bf16*)(ws + 30 * MB);  // 2 MB
    __bf16* q_ws = (__bf16*)(ws + 32 * MB);  // 8 MB
    __bf16* k_ws = (__bf16*)(ws + 40 * MB);  // 8 MB
    __bf16* v_ws = (__bf16*)(ws + 48 * MB);  // 8 MB  (total 56 MB)
    __bf16* attb = qb;                       // alias: qb dead after qkv_kernel
    float*  out  = (float*)d_out;

    cvt_kernel<<<dim3(2048, 1, 7), 256, 0, stream>>>(
        q_in, k_in, v_in, wq, wk, wv, wo, qb, kb, vb, wqb, wkb, wvb, wob);
    qkv_kernel<<<dim3(D_ / 128, (B_ * S_) / 128, 3), 256, 0, stream>>>(
        qb, kb, vb, wqb, wkb, wvb, bq, bk, bv, q_ws, k_ws, v_ws);
    attn_kernel<<<dim3(B_ * H_, S_ / 128), 256, 0, stream>>>(q_ws, k_ws, v_ws, attb);
    oproj_kernel<<<dim3(D_ / 128, (B_ * S_) / 128), 256, 0, stream>>>(attb, wob, bo, out);
}

// Round 5
// 242.625 us; speedup vs baseline: 1.5870x; 1.1599x over previous
//
#include <hip/hip_runtime.h>

// MultiHeadedAttention: B=2, S=2048, D=1024, H=16, DH=64.
// fp32 in/out; internal bf16 MFMA pipeline.
// cvt (fp32->bf16) -> QKV bf16 GEMMs -> flash attention (static-max) -> oproj.

typedef __bf16 bf16x8 __attribute__((ext_vector_type(8)));
typedef float  f32x4  __attribute__((ext_vector_type(4)));

#define B_  2
#define S_  2048
#define D_  1024
#define H_  16
#define DH_ 64

#define NEG_ 1.0e30f              // finite "-inf": exp2 -> 0, no inf-inf NaN
#define M2_  5.77078016f          // static softmax max: 4.0 * log2(e)
#define QSCALE_ 0.18033688f       // 1/sqrt(64) * log2(e): scores in log2 domain

#if __has_builtin(__builtin_amdgcn_exp2f)
#define EXP2(x) __builtin_amdgcn_exp2f(x)
#else
#define EXP2(x) __builtin_exp2f(x)
#endif

// ---- async 16B global -> LDS copy (lane l writes lds_base + l*16B) ---------
__device__ __forceinline__ void load_lds16(const __bf16* g, __bf16* lds_base) {
    __builtin_amdgcn_global_load_lds(
        (const __attribute__((address_space(1))) void*)g,
        (__attribute__((address_space(3))) void*)lds_base,
        16, 0, 0);
}

// ---- load 8 consecutive fp32, convert to packed bf16x8 ---------------------
__device__ __forceinline__ bf16x8 cvt8(const float* __restrict__ p) {
    const float4 a = *(const float4*)p;
    const float4 b = *(const float4*)(p + 4);
    bf16x8 r;
    r[0] = (__bf16)a.x; r[1] = (__bf16)a.y; r[2] = (__bf16)a.z; r[3] = (__bf16)a.w;
    r[4] = (__bf16)b.x; r[5] = (__bf16)b.y; r[6] = (__bf16)b.z; r[7] = (__bf16)b.w;
    return r;
}

// ---- fp32 -> bf16 conversion pass: z picks tensor --------------------------
__global__ void cvt_kernel(const float* __restrict__ q, const float* __restrict__ k,
                           const float* __restrict__ v,
                           const float* __restrict__ wq, const float* __restrict__ wk,
                           const float* __restrict__ wv, const float* __restrict__ wo,
                           __bf16* __restrict__ qb, __bf16* __restrict__ kb,
                           __bf16* __restrict__ vb,
                           __bf16* __restrict__ wqb, __bf16* __restrict__ wkb,
                           __bf16* __restrict__ wvb, __bf16* __restrict__ wob) {
    const int z = blockIdx.z;
    const float* src; __bf16* dst; size_t n;
    switch (z) {
        case 0: src = q;  dst = qb;  n = (size_t)B_ * S_ * D_; break;
        case 1: src = k;  dst = kb;  n = (size_t)B_ * S_ * D_; break;
        case 2: src = v;  dst = vb;  n = (size_t)B_ * S_ * D_; break;
        case 3: src = wq; dst = wqb; n = (size_t)D_ * D_; break;
        case 4: src = wk; dst = wkb; n = (size_t)D_ * D_; break;
        case 5: src = wv; dst = wvb; n = (size_t)D_ * D_; break;
        default: src = wo; dst = wob; n = (size_t)D_ * D_; break;
    }
    const size_t i = ((size_t)blockIdx.x * 256 + threadIdx.x) * 8;
    if (i >= n) return;
    *(bf16x8*)(dst + i) = cvt8(src + i);
}

// ---- 128x128 bf16 GEMM core: Y[m,n] = sum_k X[m,k]*W[n,k], global_load_lds -
__device__ __forceinline__ void gemm128_bf(const __bf16* __restrict__ X,
                                           const __bf16* __restrict__ W,
                                           int m0, int n0, int K,
                                           __bf16* As, __bf16* Bs,
                                           f32x4 acc[4][4]) {
    const int tid  = threadIdx.x;
    const int wave = tid >> 6, lane = tid & 63;
    const int row  = lane & 15, quad = lane >> 4;
    const int wm   = wave >> 1, wn = wave & 1;
    const int arow = lane >> 2;        // 0..15 row within 16-row chunk
    const int acol = (lane & 3) * 8;   // elem offset within 32-elem row

    const f32x4 fzero = {0.f, 0.f, 0.f, 0.f};
#pragma unroll
    for (int mt = 0; mt < 4; ++mt)
#pragma unroll
        for (int nt = 0; nt < 4; ++nt) acc[mt][nt] = fzero;

    for (int k0 = 0; k0 < K; k0 += 32) {
#pragma unroll
        for (int c = 0; c < 2; ++c) {
            const int j = wave * 2 + c;  // chunk 0..7, 16 rows each
            load_lds16(X + (size_t)(m0 + j * 16 + arow) * K + k0 + acol, As + j * 512);
            load_lds16(W + (size_t)(n0 + j * 16 + arow) * K + k0 + acol, Bs + j * 512);
        }
        __syncthreads();
        bf16x8 af[4], bfv[4];
#pragma unroll
        for (int t = 0; t < 4; ++t) {
            af[t]  = *(const bf16x8*)(As + (wm * 64 + t * 16 + row) * 32 + quad * 8);
            bfv[t] = *(const bf16x8*)(Bs + (wn * 64 + t * 16 + row) * 32 + quad * 8);
        }
#pragma unroll
        for (int mt = 0; mt < 4; ++mt)
#pragma unroll
            for (int nt = 0; nt < 4; ++nt)
                acc[mt][nt] = __builtin_amdgcn_mfma_f32_16x16x32_bf16(
                    af[mt], bfv[nt], acc[mt][nt], 0, 0, 0);
        __syncthreads();
    }
}

// ---- QKV projection (bf16): z selects Q/K/V. Head-split layouts. ----------
__global__ void qkv_kernel(const __bf16* __restrict__ qb, const __bf16* __restrict__ kb,
                           const __bf16* __restrict__ vb,
                           const __bf16* __restrict__ wqb, const __bf16* __restrict__ wkb,
                           const __bf16* __restrict__ wvb,
                           const float* __restrict__ bq, const float* __restrict__ bk,
                           const float* __restrict__ bv,
                           __bf16* __restrict__ q_ws, __bf16* __restrict__ k_ws,
                           __bf16* __restrict__ v_ws) {
    __shared__ __align__(16) __bf16 As[128 * 32];
    __shared__ __align__(16) __bf16 Bs[128 * 32];
    const int mode = blockIdx.z;
    const __bf16* X    = mode == 0 ? qb : mode == 1 ? kb : vb;
    const __bf16* W    = mode == 0 ? wqb : mode == 1 ? wkb : wvb;
    const float*  bias = mode == 0 ? bq : mode == 1 ? bk : bv;
    const int m0 = blockIdx.y * 128, n0 = blockIdx.x * 128;

    f32x4 acc[4][4];
    gemm128_bf(X, W, m0, n0, D_, As, Bs, acc);

    const int tid = threadIdx.x;
    const int wave = tid >> 6, lane = tid & 63;
    const int row = lane & 15, quad = lane >> 4;
    const int wm = wave >> 1, wn = wave & 1;

#pragma unroll
    for (int nt = 0; nt < 4; ++nt) {
        const int n  = n0 + wn * 64 + nt * 16 + row;
        const float bf = bias[n];
        const int h = n >> 6, dh = n & 63;
#pragma unroll
        for (int mt = 0; mt < 4; ++mt) {
#pragma unroll
            for (int r = 0; r < 4; ++r) {
                const int m = m0 + wm * 64 + mt * 16 + quad * 4 + r;
                const int bb = m >> 11, s = m & (S_ - 1);
                const float val = acc[mt][nt][r] + bf;
                if (mode == 0)       // Q: (B,H,S,DH), scaled to log2 domain
                    q_ws[(((size_t)bb * H_ + h) * S_ + s) * DH_ + dh] = (__bf16)(val * QSCALE_);
                else if (mode == 1)  // K: (B,H,S,DH)
                    k_ws[(((size_t)bb * H_ + h) * S_ + s) * DH_ + dh] = (__bf16)val;
                else                 // V: transposed (B,H,DH,S)
                    v_ws[(((size_t)bb * H_ + h) * DH_ + dh) * S_ + s] = (__bf16)val;
            }
        }
    }
}

// ---- Flash attention, static-max softmax, 32-key slices. bf16 att out. -----
// LDS: Ks 16K + Vs 16K + Ps 8K = 40 KB -> 4 WG/CU.
__global__ void attn_kernel(const __bf16* __restrict__ q_ws, const __bf16* __restrict__ k_ws,
                            const __bf16* __restrict__ v_ws, __bf16* __restrict__ att) {
    __shared__ __align__(16) __bf16 Ks[128 * 64];    // [key][dh]
    __shared__ __align__(16) __bf16 Vs[64 * 128];    // [dh][key]  (transposed V)
    __shared__ __align__(16) __bf16 Ps[4 * 32 * 32]; // per-wave P slice [32 rows][32 keys]

    const int bh = blockIdx.x;                 // b*H + h
    const int qt = (S_ / 128 - 1) - blockIdx.y; // heavy blocks dispatch first
    const int tid = threadIdx.x, wave = tid >> 6, lane = tid & 63;
    const int row = lane & 15, quad = lane >> 4;

    const __bf16* Qg = q_ws + ((size_t)bh * S_ + qt * 128 + wave * 32) * DH_;
    const __bf16* Kg = k_ws + (size_t)bh * S_ * DH_;
    const __bf16* Vg = v_ws + (size_t)bh * DH_ * S_;
    __bf16* Pw = Ps + wave * 1024;             // this wave's 32x32 P slice

    // Q fragments: A layout, rows wave*32 + mt*16 + row, k = ks*32+quad*8..+7
    bf16x8 qf[2][2];
#pragma unroll
    for (int mt = 0; mt < 2; ++mt)
#pragma unroll
        for (int ks = 0; ks < 2; ++ks)
            qf[mt][ks] = *(const bf16x8*)(Qg + (mt * 16 + row) * DH_ + ks * 32 + quad * 8);

    // all-ones B fragment (register constant) for row-sum via MFMA
    bf16x8 onesf;
#pragma unroll
    for (int i = 0; i < 8; ++i) onesf[i] = (__bf16)1.0f;

    const f32x4 fzero = {0.f, 0.f, 0.f, 0.f};
    f32x4 oacc[2][4];   // O accumulator
    f32x4 lacc[2];      // row-sum accumulator (col-redundant)
#pragma unroll
    for (int mt = 0; mt < 2; ++mt) {
#pragma unroll
        for (int dt = 0; dt < 4; ++dt) oacc[mt][dt] = fzero;
        lacc[mt] = fzero;
    }

    for (int kv = 0; kv <= qt; ++kv) {
        // stage K tile (16KB) and Vt tile (64 rows x 256B)
#pragma unroll
        for (int c = 0; c < 4; ++c) {
            const int ck = wave * 4 + c;  // chunk 0..15, 1KB each
            load_lds16(Kg + (size_t)kv * 128 * DH_ + ck * 512 + lane * 8, Ks + ck * 512);
            load_lds16(Vg + (size_t)(ck * 4 + (lane >> 4)) * S_ + kv * 128 + (lane & 15) * 8,
                       Vs + ck * 512);
        }
        __syncthreads();

        const bool diag = (kv == qt);
        // process 128 keys in four 32-key slices: QK^T -> exp -> P -> PV
#pragma unroll
        for (int kc = 0; kc < 4; ++kc) {
            // S-slice = Q K^T for keys kc*32 .. kc*32+31 (2 n-tiles)
            f32x4 s[2][2];
#pragma unroll
            for (int mt = 0; mt < 2; ++mt)
#pragma unroll
                for (int jn = 0; jn < 2; ++jn) s[mt][jn] = fzero;
#pragma unroll
            for (int jn = 0; jn < 2; ++jn) {
                const int nt = kc * 2 + jn;
                bf16x8 kf0 = *(const bf16x8*)(Ks + (nt * 16 + row) * DH_ + quad * 8);
                bf16x8 kf1 = *(const bf16x8*)(Ks + (nt * 16 + row) * DH_ + 32 + quad * 8);
#pragma unroll
                for (int mt = 0; mt < 2; ++mt) {
                    s[mt][jn] = __builtin_amdgcn_mfma_f32_16x16x32_bf16(qf[mt][0], kf0, s[mt][jn], 0, 0, 0);
                    s[mt][jn] = __builtin_amdgcn_mfma_f32_16x16x32_bf16(qf[mt][1], kf1, s[mt][jn], 0, 0, 0);
                }
            }

            if (diag) {  // causal mask: col > row -> masked
#pragma unroll
                for (int mt = 0; mt < 2; ++mt)
#pragma unroll
                    for (int jn = 0; jn < 2; ++jn) {
                        const int cloc = kc * 32 + jn * 16 + row;
#pragma unroll
                        for (int r = 0; r < 4; ++r) {
                            const int rloc = wave * 32 + mt * 16 + quad * 4 + r;
                            if (cloc > rloc) s[mt][jn][r] = -NEG_;
                        }
                    }
            }

            // p = 2^(s - M2); write 32x32 slice (wave-private; lgkm RAW by compiler)
#pragma unroll
            for (int mt = 0; mt < 2; ++mt)
#pragma unroll
                for (int r = 0; r < 4; ++r)
#pragma unroll
                    for (int jn = 0; jn < 2; ++jn) {
                        const float p = EXP2(s[mt][jn][r] - M2_);
                        Pw[(mt * 16 + quad * 4 + r) * 32 + jn * 16 + row] = (__bf16)p;
                    }

            // O += P V ; l += P 1   (K-dim = 32 keys of this slice)
            bf16x8 pf0 = *(const bf16x8*)(Pw + (row) * 32 + quad * 8);
            bf16x8 pf1 = *(const bf16x8*)(Pw + (16 + row) * 32 + quad * 8);
#pragma unroll
            for (int dt = 0; dt < 4; ++dt) {
                bf16x8 vf = *(const bf16x8*)(Vs + (dt * 16 + row) * 128 + kc * 32 + quad * 8);
                oacc[0][dt] = __builtin_amdgcn_mfma_f32_16x16x32_bf16(pf0, vf, oacc[0][dt], 0, 0, 0);
                oacc[1][dt] = __builtin_amdgcn_mfma_f32_16x16x32_bf16(pf1, vf, oacc[1][dt], 0, 0, 0);
            }
            lacc[0] = __builtin_amdgcn_mfma_f32_16x16x32_bf16(pf0, onesf, lacc[0], 0, 0, 0);
            lacc[1] = __builtin_amdgcn_mfma_f32_16x16x32_bf16(pf1, onesf, lacc[1], 0, 0, 0);
        }
        __syncthreads();  // all waves done with Ks/Vs before next staging
    }

    // epilogue: O / l, write merged layout (B, S, H*DH) in bf16
    const int b = bh >> 4, h = bh & 15;
#pragma unroll
    for (int mt = 0; mt < 2; ++mt) {
#pragma unroll
        for (int r = 0; r < 4; ++r) {
            const float inv = 1.f / lacc[mt][r];
            const int s = qt * 128 + wave * 32 + mt * 16 + quad * 4 + r;
#pragma unroll
            for (int dt = 0; dt < 4; ++dt) {
                att[((size_t)b * S_ + s) * D_ + h * DH_ + dt * 16 + row] =
                    (__bf16)(oacc[mt][dt][r] * inv);
            }
        }
    }
}

// ---- Output projection: out = att @ W_O^T + b_O (bf16 in, fp32 out) -------
__global__ void oproj_kernel(const __bf16* __restrict__ attn, const __bf16* __restrict__ wob,
                             const float* __restrict__ bo, float* __restrict__ out) {
    __shared__ __align__(16) __bf16 As[128 * 32];
    __shared__ __align__(16) __bf16 Bs[128 * 32];
    const int m0 = blockIdx.y * 128, n0 = blockIdx.x * 128;

    f32x4 acc[4][4];
    gemm128_bf(attn, wob, m0, n0, D_, As, Bs, acc);

    const int tid = threadIdx.x;
    const int wave = tid >> 6, lane = tid & 63;
    const int row = lane & 15, quad = lane >> 4;
    const int wm = wave >> 1, wn = wave & 1;

#pragma unroll
    for (int nt = 0; nt < 4; ++nt) {
        const int n = n0 + wn * 64 + nt * 16 + row;
        const float bf = bo[n];
#pragma unroll
        for (int mt = 0; mt < 4; ++mt) {
#pragma unroll
            for (int r = 0; r < 4; ++r) {
                const int m = m0 + wm * 64 + mt * 16 + quad * 4 + r;
                out[(size_t)m * D_ + n] = acc[mt][nt][r] + bf;
            }
        }
    }
}

extern "C" void kernel_launch(void* const* d_in, const int* in_sizes, int n_in,
                              void* d_out, int out_size, void* d_ws, size_t ws_size,
                              hipStream_t stream) {
    const float* q_in = (const float*)d_in[0];
    const float* k_in = (const float*)d_in[1];
    const float* v_in = (const float*)d_in[2];
    const float* wq   = (const float*)d_in[3];
    const float* bq   = (const float*)d_in[4];
    const float* wk   = (const float*)d_in[5];
    const float* bk   = (const float*)d_in[6];
    const float* wv   = (const float*)d_in[7];
    const float* bv   = (const float*)d_in[8];
    const float* wo   = (const float*)d_in[9];
    const float* bo   = (const float*)d_in[10];

    char* ws = (char*)d_ws;
    const size_t MB = 1024 * 1024;
    __bf16* qb   = (__bf16*)(ws);            // 8 MB
    __bf16* kb   = (__bf16*)(ws + 8 * MB);   // 8 MB
    __bf16* vb   = (__bf16*)(ws + 16 * MB);  // 8 MB
    __bf16* wqb  = (__bf16*)(ws + 24 * MB);  // 2 MB
    __bf16* wkb  = (__bf16*)(ws + 26 * MB);  // 2 MB
    __bf16* wvb  = (__bf16*)(ws + 28 * MB);  // 2 MB
    __bf16* wob  = (__bf16*)(ws + 30 * MB);  // 2 MB
    __bf16* q_ws = (__bf16*)(ws + 32 * MB);  // 8 MB
    __bf16* k_ws = (__bf16*)(ws + 40 * MB);  // 8 MB
    __bf16* v_ws = (__bf16*)(ws + 48 * MB);  // 8 MB  (total 56 MB)
    __bf16* attb = qb;                       // alias: qb dead after qkv_kernel
    float*  out  = (float*)d_out;

    cvt_kernel<<<dim3(2048, 1, 7), 256, 0, stream>>>(
        q_in, k_in, v_in, wq, wk, wv, wo, qb, kb, vb, wqb, wkb, wvb, wob);
    qkv_kernel<<<dim3(D_ / 128, (B_ * S_) / 128, 3), 256, 0, stream>>>(
        qb, kb, vb, wqb, wkb, wvb, bq, bk, bv, q_ws, k_ws, v_ws);
    attn_kernel<<<dim3(B_ * H_, S_ / 128), 256, 0, stream>>>(q_ws, k_ws, v_ws, attb);
    oproj_kernel<<<dim3(D_ / 128, (B_ * S_) / 128), 256, 0, stream>>>(attb, wob, bo, out);
}